// Round 7
// baseline (327.381 us; speedup 1.0000x reference)
//
#include <hip/hip_runtime.h>

typedef unsigned short u16;
typedef unsigned int u32;
typedef u16 u16x8 __attribute__((ext_vector_type(8)));
typedef u16 u16x4 __attribute__((ext_vector_type(4)));
typedef float f32x4 __attribute__((ext_vector_type(4)));
typedef __bf16 bf16x8 __attribute__((ext_vector_type(8)));

#define NHEAD 12
#define NT 261
#define NGL 197
#define CDIM 768
#define KT 14
#define PS_STRIDE 232
#define VT_STRIDE 232

__device__ __forceinline__ float bf2f(u16 u) {
    u32 x = ((u32)u) << 16;
    float f;
    __builtin_memcpy(&f, &x, 4);
    return f;
}
__device__ __forceinline__ u16 f2bf(float f) {
    u32 x;
    __builtin_memcpy(&x, &f, 4);
    x = (x + 0x7fffu + ((x >> 16) & 1u)) >> 16;
    return (u16)x;
}

#define GLD_LDS16(g, l) \
    __builtin_amdgcn_global_load_lds((const __attribute__((address_space(1))) void*)(g), \
                                     (__attribute__((address_space(3))) void*)(l), 16, 0, 0)
#define WAITV(n) asm volatile("s_waitcnt vmcnt(" #n ")" ::: "memory")
#define LGKM0()  asm volatile("s_waitcnt lgkmcnt(0)" ::: "memory")
#define BARM() asm volatile("s_barrier" ::: "memory")

// ---------------- fp32 -> bf16 weight conversion (all 4 weights, one launch) ----------------
struct CvArgs {
    const float* in[4];
    u16* out[4];
    int n4[4];
};
__global__ __launch_bounds__(256) void convk4(CvArgs a) {
    int y = blockIdx.y;
    const float* in = a.in[y];
    u16* out = a.out[y];
    int n4 = a.n4[y];
    int i = blockIdx.x * 256 + threadIdx.x;
    if (i >= n4) return;
    float4 v = ((const float4*)in)[i];
    u16x4 o;
    o[0] = f2bf(v.x); o[1] = f2bf(v.y); o[2] = f2bf(v.z); o[3] = f2bf(v.w);
    ((u16x4*)out)[i] = o;
}

// ---------------- LayerNorm (row of 768) -> bf16 ----------------
__global__ __launch_bounds__(256) void ln_k(const float* __restrict__ in, const float* __restrict__ w,
                                            const float* __restrict__ bia, u16* __restrict__ out) {
    int row = blockIdx.x;
    int tid = threadIdx.x;
    const float* r = in + (size_t)row * CDIM;
    float v0 = r[tid], v1 = r[tid + 256], v2 = r[tid + 512];
    float s = v0 + v1 + v2;
    float ss = v0 * v0 + v1 * v1 + v2 * v2;
#pragma unroll
    for (int off = 32; off; off >>= 1) {
        s += __shfl_xor(s, off);
        ss += __shfl_xor(ss, off);
    }
    __shared__ float ls[4], lss[4];
    int wv = tid >> 6;
    if ((tid & 63) == 0) { ls[wv] = s; lss[wv] = ss; }
    __syncthreads();
    s = ls[0] + ls[1] + ls[2] + ls[3];
    ss = lss[0] + lss[1] + lss[2] + lss[3];
    float mu = s * (1.f / 768.f);
    float var = ss * (1.f / 768.f) - mu * mu;
    float inv = rsqrtf(var + 1e-5f);
    u16* o = out + (size_t)row * CDIM;
    o[tid]       = f2bf((v0 - mu) * inv * w[tid]       + bia[tid]);
    o[tid + 256] = f2bf((v1 - mu) * inv * w[tid + 256] + bia[tid + 256]);
    o[tid + 512] = f2bf((v2 - mu) * inv * w[tid + 512] + bia[tid + 512]);
}

// ---------------- phase-interleaved MFMA GEMM: C[m,n] = sum_k A[m,k]*B[n,k] ----------------
// 256x128 tile, BK=64, 512 thr = 8 waves (4Mx2N, 64x64 wave tile, acc[4][4]).
// 3 LDS buffers (144 KiB): stage(t+2) issued during tile t (A-part phase1, B-part phase2),
// waited at tile t+2 entry only -> loads span ~8 barriers (T4 counted vmcnt).
// Per tile: vmcnt(6)+bar; 2x { stage-issue || 8 ds_read -> lgkmcnt(0) -> bar ->
//                              setprio(1) 16 MFMA setprio(0) -> bar }  (T3+T5).
// lgkmcnt(0) before the barrier drains buffer reads, making the next stage into that
// buffer race-free. 16B-slot involution swizzle via pre-swizzled global source (rule #21).
// EPI: 0 = plain -> bf16; 1 = +bias +residual(fp32) -> fp32; 2 = +bias +gelu(tanh) -> bf16
template <int EPI>
__global__ __launch_bounds__(512, 2) void gemm6(const u16* __restrict__ A, const u16* __restrict__ Bw,
                                                int M, int N, int K, int nbn,
                                                const float* __restrict__ bias,
                                                const float* __restrict__ resid, void* __restrict__ outp) {
    constexpr int BUF = 24576;                   // u16 per buffer: A 16384 | B 8192
    __shared__ __align__(16) u16 sm[3 * BUF];    // 147456 B
    const int tid = threadIdx.x;
    const int nwg = gridDim.x;
    const int q = nwg >> 3, r = nwg & 7;
    const int xcd = blockIdx.x & 7, within = blockIdx.x >> 3;
    const int id2 = (xcd < r ? xcd * (q + 1) : r * (q + 1) + (xcd - r) * q) + within;
    const int bm = id2 / nbn, bn = id2 % nbn;
    const int lane = tid & 63, wv = tid >> 6;
    const int wr = wv >> 1, wc = wv & 1;
    const int l15 = lane & 15, lg = lane >> 4;
    const int arow0 = bm * 256, brow0 = bn * 128;
    const int nt = K >> 6;

    // staging: A = 4 issues (rows i*64+srow), B = 2 issues; source col pre-swizzled
    const int srow = tid >> 3;
    const int sk = ((tid & 7) ^ (srow & 7)) * 8;
    const u16* gA[4];
    const u16* gB[2];
#pragma unroll
    for (int i = 0; i < 4; ++i) {
        int ar = arow0 + i * 64 + srow;
        if (ar >= M) ar = M - 1;
        gA[i] = A + (size_t)ar * K + sk;
    }
#pragma unroll
    for (int j = 0; j < 2; ++j)
        gB[j] = Bw + (size_t)(brow0 + j * 64 + srow) * K + sk;

    auto STAGE_A = [&](int tt) {
        u16* sb = sm + (tt % 3) * BUF;
        const size_t ko = (size_t)tt * 64;
#pragma unroll
        for (int i = 0; i < 4; ++i) GLD_LDS16(gA[i] + ko, sb + i * 4096 + tid * 8);
    };
    auto STAGE_B = [&](int tt) {
        u16* sb = sm + (tt % 3) * BUF;
        const size_t ko = (size_t)tt * 64;
#pragma unroll
        for (int j = 0; j < 2; ++j) GLD_LDS16(gB[j] + ko, sb + 16384 + j * 4096 + tid * 8);
    };

    f32x4 acc[4][4] = {};
    const int xb = l15 & 7;

    STAGE_A(0); STAGE_B(0);
    STAGE_A(1); STAGE_B(1);
    for (int t = 0; t < nt; ++t) {
        if (t + 1 < nt) { WAITV(6); } else { WAITV(0); }   // stage(t) landed; t+1 stays in flight
        BARM();
        const u16* sb = sm + (t % 3) * BUF;
        const bool pre = (t + 2 < nt);
        // ---- phase 1: stage A-part of t+2; compute kk=0 ----
        if (pre) STAGE_A(t + 2);
        bf16x8 af0[4], bq0[4];
#pragma unroll
        for (int mi = 0; mi < 4; ++mi)
            af0[mi] = *(const bf16x8*)(sb + (wr * 64 + mi * 16 + l15) * 64 + ((lg ^ xb) << 3));
#pragma unroll
        for (int ni = 0; ni < 4; ++ni)
            bq0[ni] = *(const bf16x8*)(sb + 16384 + (wc * 64 + ni * 16 + l15) * 64 + ((lg ^ xb) << 3));
        LGKM0();
        BARM();
        __builtin_amdgcn_s_setprio(1);
#pragma unroll
        for (int mi = 0; mi < 4; ++mi)
#pragma unroll
            for (int ni = 0; ni < 4; ++ni)
                acc[mi][ni] = __builtin_amdgcn_mfma_f32_16x16x32_bf16(af0[mi], bq0[ni], acc[mi][ni], 0, 0, 0);
        __builtin_amdgcn_s_setprio(0);
        BARM();
        // ---- phase 2: stage B-part of t+2; compute kk=1 ----
        if (pre) STAGE_B(t + 2);
        bf16x8 af1[4], bq1[4];
#pragma unroll
        for (int mi = 0; mi < 4; ++mi)
            af1[mi] = *(const bf16x8*)(sb + (wr * 64 + mi * 16 + l15) * 64 + (((4 | lg) ^ xb) << 3));
#pragma unroll
        for (int ni = 0; ni < 4; ++ni)
            bq1[ni] = *(const bf16x8*)(sb + 16384 + (wc * 64 + ni * 16 + l15) * 64 + (((4 | lg) ^ xb) << 3));
        LGKM0();
        BARM();
        __builtin_amdgcn_s_setprio(1);
#pragma unroll
        for (int mi = 0; mi < 4; ++mi)
#pragma unroll
            for (int ni = 0; ni < 4; ++ni)
                acc[mi][ni] = __builtin_amdgcn_mfma_f32_16x16x32_bf16(af1[mi], bq1[ni], acc[mi][ni], 0, 0, 0);
        __builtin_amdgcn_s_setprio(0);
        // loop head's WAITV+BARM closes the tile
    }

#pragma unroll
    for (int mi = 0; mi < 4; ++mi) {
        int row0 = arow0 + wr * 64 + mi * 16 + lg * 4;
#pragma unroll
        for (int ni = 0; ni < 4; ++ni) {
            int col = brow0 + wc * 64 + ni * 16 + l15;
            float bb = (EPI == 0) ? 0.f : bias[col];
#pragma unroll
            for (int rr = 0; rr < 4; ++rr) {
                int row = row0 + rr;
                if (row < M) {
                    float v = acc[mi][ni][rr] + bb;
                    if (EPI == 2) {
                        float z = v + 0.044715f * v * v * v;
                        v = v / (1.f + __expf(-1.5957691216f * z));
                    }
                    if (EPI == 1) {
                        v += resid[(size_t)row * N + col];
                        ((float*)outp)[(size_t)row * N + col] = v;
                    } else {
                        ((u16*)outp)[(size_t)row * N + col] = f2bf(v);
                    }
                }
            }
        }
    }
}

// ---------------- Global attention via MFMA ----------------
__global__ __launch_bounds__(256) void attn_global_mfma(const u16* __restrict__ qkv, u16* __restrict__ Z) {
    __shared__ __align__(16) u16 lds0[4 * 16 * PS_STRIDE];
    __shared__ __align__(16) u16 Vt[64 * VT_STRIDE];
    const int tid = threadIdx.x;
    const int blk = blockIdx.x;
    const int qt = blk & 3;
    const int bh = blk >> 2;
    const int h = bh % NHEAD, b = bh / NHEAD;
    const int lane = tid & 63, wv = tid >> 6;
    const int l15 = lane & 15, lg = lane >> 4;
    const u16* base = qkv + (size_t)b * NT * 2304;

    for (int c = tid; c < 224 * 8; c += 256) {
        int row = c >> 3, ch = c & 7;
        u16x8 v = {};
        if (row < NGL) v = *(const u16x8*)(base + (size_t)row * 2304 + 768 + h * 64 + ch * 8);
        int byte = row * 128 + ((ch * 16) ^ ((row & 7) << 4));
        *(u16x8*)((char*)lds0 + byte) = v;
    }
    for (int c = tid; c < 112 * 8; c += 256) {
        int mp = c >> 3, dch = c & 7;
        int m0 = mp * 2;
        u16x8 a0 = {}, a1 = {};
        if (m0 < NGL)     a0 = *(const u16x8*)(base + (size_t)m0 * 2304 + 1536 + h * 64 + dch * 8);
        if (m0 + 1 < NGL) a1 = *(const u16x8*)(base + (size_t)(m0 + 1) * 2304 + 1536 + h * 64 + dch * 8);
#pragma unroll
        for (int j = 0; j < 8; ++j) {
            u32 pk = (u32)a0[j] | ((u32)a1[j] << 16);
            *(u32*)((char*)Vt + (size_t)(dch * 8 + j) * (VT_STRIDE * 2) + m0 * 2) = pk;
        }
    }
    const int q0 = qt * 64 + wv * 16;
    int qrow = q0 + l15; if (qrow > NGL - 1) qrow = NGL - 1;
    bf16x8 aq0 = *(const bf16x8*)(base + (size_t)qrow * 2304 + h * 64 + lg * 8);
    bf16x8 aq1 = *(const bf16x8*)(base + (size_t)qrow * 2304 + h * 64 + 32 + lg * 8);
    __syncthreads();

    f32x4 s[KT];
    const int sw = (l15 & 7) << 4;
#pragma unroll
    for (int t = 0; t < KT; ++t) {
        const char* krow = (const char*)lds0 + (t * 16 + l15) * 128;
        bf16x8 bk0 = *(const bf16x8*)(krow + ((lg * 16) ^ sw));
        bf16x8 bk1 = *(const bf16x8*)(krow + ((64 + lg * 16) ^ sw));
        f32x4 acc = {};
        acc = __builtin_amdgcn_mfma_f32_16x16x32_bf16(aq0, bk0, acc, 0, 0, 0);
        acc = __builtin_amdgcn_mfma_f32_16x16x32_bf16(aq1, bk1, acc, 0, 0, 0);
        s[t] = acc * 0.125f;
    }
    float mx[4] = {-1e30f, -1e30f, -1e30f, -1e30f};
#pragma unroll
    for (int t = 0; t < KT; ++t)
#pragma unroll
        for (int r = 0; r < 4; ++r) mx[r] = fmaxf(mx[r], s[t][r]);
#pragma unroll
    for (int off = 1; off < 16; off <<= 1)
#pragma unroll
        for (int r = 0; r < 4; ++r) mx[r] = fmaxf(mx[r], __shfl_xor(mx[r], off));
    float sum[4] = {};
#pragma unroll
    for (int t = 0; t < KT; ++t) {
        bool valid = (t * 16 + l15) < NGL;
#pragma unroll
        for (int r = 0; r < 4; ++r) {
            float e = valid ? __expf(s[t][r] - mx[r]) : 0.f;
            s[t][r] = e;
            sum[r] += e;
        }
    }
#pragma unroll
    for (int off = 1; off < 16; off <<= 1)
#pragma unroll
        for (int r = 0; r < 4; ++r) sum[r] += __shfl_xor(sum[r], off);
    float inv[4];
#pragma unroll
    for (int r = 0; r < 4; ++r) inv[r] = 1.f / sum[r];

    __syncthreads();
    u16* Pw = lds0 + wv * 16 * PS_STRIDE;
#pragma unroll
    for (int t = 0; t < KT; ++t)
#pragma unroll
        for (int r = 0; r < 4; ++r)
            Pw[(4 * lg + r) * PS_STRIDE + t * 16 + l15] = f2bf(s[t][r] * inv[r]);

    f32x4 o[4] = {};
#pragma unroll
    for (int ks = 0; ks < 7; ++ks) {
        bf16x8 pa = *(const bf16x8*)(Pw + l15 * PS_STRIDE + ks * 32 + lg * 8);
#pragma unroll
        for (int dt = 0; dt < 4; ++dt) {
            bf16x8 bv = *(const bf16x8*)((const char*)Vt + (size_t)(dt * 16 + l15) * (VT_STRIDE * 2) + ks * 64 + lg * 16);
            o[dt] = __builtin_amdgcn_mfma_f32_16x16x32_bf16(pa, bv, o[dt], 0, 0, 0);
        }
    }
#pragma unroll
    for (int dt = 0; dt < 4; ++dt)
#pragma unroll
        for (int r = 0; r < 4; ++r) {
            int q = q0 + 4 * lg + r;
            if (q < NGL) Z[((size_t)b * NT + q) * CDIM + h * 64 + dt * 16 + l15] = f2bf(o[dt][r]);
        }
}

// ---------------- Neighborhood attention ----------------
__global__ __launch_bounds__(64) void attn_neigh(const u16* __restrict__ qkv, const float* __restrict__ ps,
                                                 u16* __restrict__ Z) {
    int blk = blockIdx.x;
    int b = blk >> 6, m = blk & 63;
    int lane = threadIdx.x;
    float px = ps[((size_t)b * 64 + m) * 2 + 0] * (1.f / 16.f);
    float py = ps[((size_t)b * 64 + m) * 2 + 1] * (1.f / 16.f);
    int c0 = min(max((int)floorf(px), 0), 13);
    int c1 = min(max((int)ceilf(px), 0), 13);
    int r0 = min(max((int)floorf(py), 0), 13);
    int r1 = min(max((int)ceilf(py), 0), 13);
    int tok[4];
    tok[0] = 1 + r0 * 14 + c0;
    tok[1] = 1 + r1 * 14 + c0;
    tok[2] = 1 + r0 * 14 + c1;
    tok[3] = 1 + r1 * 14 + c1;
    const size_t rowq = ((size_t)b * NT + NGL + m) * 2304;
#pragma unroll 1
    for (int h = 0; h < NHEAD; ++h) {
        float qv = bf2f(qkv[rowq + h * 64 + lane]);
        float a[4];
#pragma unroll
        for (int j = 0; j < 4; ++j) {
            float p = qv * bf2f(qkv[((size_t)b * NT + tok[j]) * 2304 + 768 + h * 64 + lane]);
#pragma unroll
            for (int off = 32; off; off >>= 1) p += __shfl_xor(p, off);
            a[j] = p;
        }
        float mx = fmaxf(fmaxf(a[0], a[1]), fmaxf(a[2], a[3]));
        float e0 = expf(a[0] - mx), e1 = expf(a[1] - mx), e2 = expf(a[2] - mx), e3 = expf(a[3] - mx);
        float inv = 1.f / (e0 + e1 + e2 + e3);
        float v0 = bf2f(qkv[((size_t)b * NT + tok[0]) * 2304 + 1536 + h * 64 + lane]);
        float v1 = bf2f(qkv[((size_t)b * NT + tok[1]) * 2304 + 1536 + h * 64 + lane]);
        float v2 = bf2f(qkv[((size_t)b * NT + tok[2]) * 2304 + 1536 + h * 64 + lane]);
        float v3 = bf2f(qkv[((size_t)b * NT + tok[3]) * 2304 + 1536 + h * 64 + lane]);
        float o = (e0 * v0 + e1 * v1 + e2 * v2 + e3 * v3) * inv;
        Z[((size_t)b * NT + NGL + m) * CDIM + h * 64 + lane] = f2bf(o);
    }
}

extern "C" void kernel_launch(void* const* d_in, const int* in_sizes, int n_in,
                              void* d_out, int out_size, void* d_ws, size_t ws_size,
                              hipStream_t stream) {
    const float* x      = (const float*)d_in[0];
    const float* ps     = (const float*)d_in[1];
    const float* n1w    = (const float*)d_in[3];
    const float* n1b    = (const float*)d_in[4];
    const float* qkv_w  = (const float*)d_in[5];
    const float* proj_w = (const float*)d_in[6];
    const float* proj_b = (const float*)d_in[7];
    const float* n2w    = (const float*)d_in[8];
    const float* n2b    = (const float*)d_in[9];
    const float* fc1_w  = (const float*)d_in[10];
    const float* fc1_b  = (const float*)d_in[11];
    const float* fc2_w  = (const float*)d_in[12];
    const float* fc2_b  = (const float*)d_in[13];

    char* ws = (char*)d_ws;
    const int M = 32 * NT;  // 8352
    u16* hbuf  = (u16*)ws;                               // 12,828,672 B
    u16* qkvb  = (u16*)(ws + 12828672);                  // 38,486,016 B
    u16* Zb    = (u16*)(ws + 12828672 + 38486016);       // 12,828,672 B
    u16* Gb    = (u16*)(ws + 12828672);                  // 51,314,688 B (aliases qkv+Z, both dead)
    float* x1  = (float*)(ws + 64143360);                // 25,657,344 B
    u16* wq    = (u16*)(ws + 89800704);
    u16* wp    = wq + 2304 * 768;
    u16* w1    = wp + 768 * 768;
    u16* w2    = w1 + 3072 * 768;

    CvArgs cv;
    cv.in[0] = qkv_w;  cv.out[0] = wq; cv.n4[0] = 2304 * 768 / 4;
    cv.in[1] = proj_w; cv.out[1] = wp; cv.n4[1] = 768 * 768 / 4;
    cv.in[2] = fc1_w;  cv.out[2] = w1; cv.n4[2] = 3072 * 768 / 4;
    cv.in[3] = fc2_w;  cv.out[3] = w2; cv.n4[3] = 768 * 3072 / 4;
    convk4<<<dim3((3072 * 768 / 4 + 255) / 256, 4), 256, 0, stream>>>(cv);

    ln_k<<<M, 256, 0, stream>>>(x, n1w, n1b, hbuf);
    gemm6<0><<<33 * 18, 512, 0, stream>>>(hbuf, wq, M, 2304, 768, 18, nullptr, nullptr, qkvb);
    attn_global_mfma<<<32 * NHEAD * 4, 256, 0, stream>>>(qkvb, Zb);
    attn_neigh<<<32 * 64, 64, 0, stream>>>(qkvb, ps, Zb);
    gemm6<1><<<33 * 6, 512, 0, stream>>>(Zb, wp, M, 768, 768, 6, proj_b, x, x1);
    ln_k<<<M, 256, 0, stream>>>(x1, n2w, n2b, hbuf);
    gemm6<2><<<33 * 24, 512, 0, stream>>>(hbuf, w1, M, 3072, 768, 24, fc1_b, nullptr, Gb);
    gemm6<1><<<33 * 6, 512, 0, stream>>>(Gb, w2, M, 768, 3072, 6, fc2_b, x1, (float*)d_out);
}

// Round 8
// 301.977 us; speedup vs baseline: 1.0841x; 1.0841x over previous
//
#include <hip/hip_runtime.h>

typedef unsigned short u16;
typedef unsigned int u32;
typedef u16 u16x8 __attribute__((ext_vector_type(8)));
typedef u16 u16x4 __attribute__((ext_vector_type(4)));
typedef float f32x4 __attribute__((ext_vector_type(4)));
typedef __bf16 bf16x8 __attribute__((ext_vector_type(8)));

#define NHEAD 12
#define NT 261
#define NGL 197
#define CDIM 768
#define KT 14
#define PS_STRIDE 232
#define VT_STRIDE 232

__device__ __forceinline__ float bf2f(u16 u) {
    u32 x = ((u32)u) << 16;
    float f;
    __builtin_memcpy(&f, &x, 4);
    return f;
}
__device__ __forceinline__ u16 f2bf(float f) {
    u32 x;
    __builtin_memcpy(&x, &f, 4);
    x = (x + 0x7fffu + ((x >> 16) & 1u)) >> 16;
    return (u16)x;
}

#define GLD_LDS16(g, l) \
    __builtin_amdgcn_global_load_lds((const __attribute__((address_space(1))) void*)(g), \
                                     (__attribute__((address_space(3))) void*)(l), 16, 0, 0)
#define WAITV(n) asm volatile("s_waitcnt vmcnt(" #n ")" ::: "memory")
#define BARM() asm volatile("s_barrier" ::: "memory")

struct CvArgs {
    const float* in[4];
    u16* out[4];
    int n4[4];
};

// ---------------- wave-per-row LayerNorm (768 cols): float4 loads, 6-shfl reduce ----------------
__device__ __forceinline__ void ln_row(const float* __restrict__ in, const float* __restrict__ w,
                                       const float* __restrict__ bia, u16* __restrict__ out,
                                       int row, int lane) {
    const float4* r = (const float4*)(in + (size_t)row * CDIM);
    float4 a = r[lane], b4 = r[lane + 64], c4 = r[lane + 128];
    float s  = a.x + a.y + a.z + a.w + b4.x + b4.y + b4.z + b4.w + c4.x + c4.y + c4.z + c4.w;
    float ss = a.x*a.x + a.y*a.y + a.z*a.z + a.w*a.w
             + b4.x*b4.x + b4.y*b4.y + b4.z*b4.z + b4.w*b4.w
             + c4.x*c4.x + c4.y*c4.y + c4.z*c4.z + c4.w*c4.w;
#pragma unroll
    for (int off = 32; off; off >>= 1) {
        s  += __shfl_xor(s, off);
        ss += __shfl_xor(ss, off);
    }
    float mu = s * (1.f / 768.f);
    float var = ss * (1.f / 768.f) - mu * mu;
    float inv = rsqrtf(var + 1e-5f);
    const float4* wp = (const float4*)w;
    const float4* bp = (const float4*)bia;
    u16* o = out + (size_t)row * CDIM;
#pragma unroll
    for (int t = 0; t < 3; ++t) {
        float4 v = (t == 0) ? a : (t == 1) ? b4 : c4;
        float4 ww = wp[lane + t * 64], bb = bp[lane + t * 64];
        u16x4 ov;
        ov[0] = f2bf((v.x - mu) * inv * ww.x + bb.x);
        ov[1] = f2bf((v.y - mu) * inv * ww.y + bb.y);
        ov[2] = f2bf((v.z - mu) * inv * ww.z + bb.z);
        ov[3] = f2bf((v.w - mu) * inv * ww.w + bb.w);
        *(u16x4*)(o + t * 256 + lane * 4) = ov;
    }
}

// y=0: weight fp32->bf16 conversion (flat over 4 segments); y=1: LN1 (4 rows/block)
__global__ __launch_bounds__(256) void pre_k(const float* __restrict__ x, const float* __restrict__ w,
                                             const float* __restrict__ bia, u16* __restrict__ out,
                                             int nrows, CvArgs cv) {
    if (blockIdx.y == 0) {
        int i = blockIdx.x * 256 + threadIdx.x;
        int s0 = cv.n4[0], s1 = s0 + cv.n4[1], s2 = s1 + cv.n4[2], s3 = s2 + cv.n4[3];
        const float* in;
        u16* o;
        int base;
        if (i < s0)      { in = cv.in[0]; o = cv.out[0]; base = 0; }
        else if (i < s1) { in = cv.in[1]; o = cv.out[1]; base = s0; }
        else if (i < s2) { in = cv.in[2]; o = cv.out[2]; base = s1; }
        else if (i < s3) { in = cv.in[3]; o = cv.out[3]; base = s2; }
        else return;
        int j = i - base;
        float4 v = ((const float4*)in)[j];
        u16x4 ov;
        ov[0] = f2bf(v.x); ov[1] = f2bf(v.y); ov[2] = f2bf(v.z); ov[3] = f2bf(v.w);
        ((u16x4*)o)[j] = ov;
    } else {
        int lane = threadIdx.x & 63, wv = threadIdx.x >> 6;
        int row = blockIdx.x * 4 + wv;
        if (row < nrows) ln_row(x, w, bia, out, row, lane);
    }
}

__global__ __launch_bounds__(256) void ln_w(const float* __restrict__ in, const float* __restrict__ w,
                                            const float* __restrict__ bia, u16* __restrict__ out, int nrows) {
    int lane = threadIdx.x & 63, wv = threadIdx.x >> 6;
    int row = blockIdx.x * 4 + wv;
    if (row < nrows) ln_row(in, w, bia, out, row, lane);
}

// ---------------- 256x256 MFMA GEMM, 128x64 wave tiles (r6 best-known) ----------------
template <int EPI>
__global__ __launch_bounds__(512, 2) void gemm5(const u16* __restrict__ A, const u16* __restrict__ Bw,
                                                int M, int N, int K, int nbn,
                                                const float* __restrict__ bias,
                                                void* __restrict__ outp) {
    __shared__ __align__(16) u16 sm[2][32768];
    const int tid = threadIdx.x;
    const int nwg = gridDim.x;
    const int q = nwg >> 3, r = nwg & 7;
    const int xcd = blockIdx.x & 7, within = blockIdx.x >> 3;
    const int id2 = (xcd < r ? xcd * (q + 1) : r * (q + 1) + (xcd - r) * q) + within;
    const int bm = id2 / nbn, bn = id2 % nbn;
    const int lane = tid & 63, wv = tid >> 6;
    const int wr = wv >> 2, wc = wv & 3;
    const int l15 = lane & 15, lg = lane >> 4;
    const int arow0 = bm * 256, brow0 = bn * 256;
    const int nt = K >> 6;

    const int srow = tid >> 3;
    const int sk = ((tid & 7) ^ (srow & 7)) * 8;
    const u16* gA[4];
    const u16* gB[4];
#pragma unroll
    for (int i = 0; i < 4; ++i) {
        int ar = arow0 + i * 64 + srow;
        if (ar >= M) ar = M - 1;
        gA[i] = A + (size_t)ar * K + sk;
        gB[i] = Bw + (size_t)(brow0 + i * 64 + srow) * K + sk;
    }

    auto STAGE = [&](int tt) {
        u16* sb = sm[tt & 1];
        const size_t ko = (size_t)tt * 64;
#pragma unroll
        for (int i = 0; i < 4; ++i) GLD_LDS16(gA[i] + ko, sb + i * 4096 + tid * 8);
#pragma unroll
        for (int i = 0; i < 4; ++i) GLD_LDS16(gB[i] + ko, sb + 16384 + i * 4096 + tid * 8);
    };

    f32x4 acc[8][4] = {};
    const int xb = l15 & 7;

    STAGE(0);
    for (int t = 0; t < nt; ++t) {
        if (t + 1 < nt) {
            STAGE(t + 1);
            WAITV(8);
        } else {
            WAITV(0);
        }
        BARM();
        const u16* sb = sm[t & 1];
        bf16x8 bq[4][2];
#pragma unroll
        for (int ni = 0; ni < 4; ++ni)
#pragma unroll
            for (int kk = 0; kk < 2; ++kk)
                bq[ni][kk] = *(const bf16x8*)(sb + 16384 + (wc * 64 + ni * 16 + l15) * 64 + (((kk << 2) | lg) ^ xb) * 8);
#pragma unroll
        for (int mi = 0; mi < 8; ++mi) {
            const u16* arow = sb + (wr * 128 + mi * 16 + l15) * 64;
            bf16x8 a0 = *(const bf16x8*)(arow + ((lg ^ xb) * 8));
            bf16x8 a1 = *(const bf16x8*)(arow + (((4 | lg) ^ xb) * 8));
#pragma unroll
            for (int ni = 0; ni < 4; ++ni) {
                acc[mi][ni] = __builtin_amdgcn_mfma_f32_16x16x32_bf16(a0, bq[ni][0], acc[mi][ni], 0, 0, 0);
                acc[mi][ni] = __builtin_amdgcn_mfma_f32_16x16x32_bf16(a1, bq[ni][1], acc[mi][ni], 0, 0, 0);
            }
        }
        if (t + 2 < nt) BARM();
    }

#pragma unroll
    for (int mi = 0; mi < 8; ++mi) {
        int row0 = arow0 + wr * 128 + mi * 16 + lg * 4;
#pragma unroll
        for (int ni = 0; ni < 4; ++ni) {
            int col = brow0 + wc * 64 + ni * 16 + l15;
            float bb = (EPI == 0) ? 0.f : bias[col];
#pragma unroll
            for (int rr = 0; rr < 4; ++rr) {
                int row = row0 + rr;
                if (row < M) {
                    float v = acc[mi][ni][rr] + bb;
                    if (EPI == 2) {
                        float z = v + 0.044715f * v * v * v;
                        v = v / (1.f + __expf(-1.5957691216f * z));
                    }
                    ((u16*)outp)[(size_t)row * N + col] = f2bf(v);
                }
            }
        }
    }
}

// ---------------- 128x128 pipelined GEMM (narrow-N): +bias +resid(fp32) -> fp32 ----------------
__global__ __launch_bounds__(256, 2) void gemm4n(const u16* __restrict__ A, const u16* __restrict__ Bw,
                                                 int M, int N, int K, int nbn,
                                                 const float* __restrict__ bias,
                                                 const float* __restrict__ resid, void* __restrict__ outp) {
    constexpr int SLOT = 128 * 64 + 8192;
    __shared__ __align__(16) u16 sm[2 * SLOT];
    const int tid = threadIdx.x;
    const int nwg = gridDim.x;
    const int q = nwg >> 3, r = nwg & 7;
    const int xcd = blockIdx.x & 7, within = blockIdx.x >> 3;
    const int id2 = (xcd < r ? xcd * (q + 1) : r * (q + 1) + (xcd - r) * q) + within;
    const int bm = id2 / nbn, bn = id2 % nbn;
    const int lane = tid & 63, wv = tid >> 6;
    const int wr = wv >> 1, wc = wv & 1;
    const int l15 = lane & 15, lg = lane >> 4;
    const int arow0 = bm * 128, brow0 = bn * 128;
    const int nt = K >> 6;

    const int srow = tid >> 3;
    const int sk = ((tid & 7) ^ (srow & 7)) * 8;
    const u16* gA[4];
    const u16* gB[4];
#pragma unroll
    for (int i = 0; i < 4; ++i) {
        int ar = arow0 + i * 32 + srow;
        if (ar >= M) ar = M - 1;
        gA[i] = A + (size_t)ar * K + sk;
        gB[i] = Bw + (size_t)(brow0 + i * 32 + srow) * K + sk;
    }

    auto STAGE = [&](int tt) {
        u16* sb = sm + (tt & 1) * SLOT;
        const size_t ko = (size_t)tt * 64;
#pragma unroll
        for (int i = 0; i < 4; ++i) GLD_LDS16(gA[i] + ko, sb + i * 2048 + tid * 8);
#pragma unroll
        for (int i = 0; i < 4; ++i) GLD_LDS16(gB[i] + ko, sb + 8192 + i * 2048 + tid * 8);
    };

    f32x4 acc[4][4] = {};
    const int xb = l15 & 7;

    STAGE(0);
    for (int t = 0; t < nt; ++t) {
        if (t + 1 < nt) {
            STAGE(t + 1);
            WAITV(8);
        } else {
            WAITV(0);
        }
        BARM();
        const u16* sb = sm + (t & 1) * SLOT;
        bf16x8 af[4][2], bq[4][2];
#pragma unroll
        for (int mi = 0; mi < 4; ++mi)
#pragma unroll
            for (int kk = 0; kk < 2; ++kk)
                af[mi][kk] = *(const bf16x8*)(sb + (wr * 64 + mi * 16 + l15) * 64 + (((kk << 2) | lg) ^ xb) * 8);
#pragma unroll
        for (int ni = 0; ni < 4; ++ni)
#pragma unroll
            for (int kk = 0; kk < 2; ++kk)
                bq[ni][kk] = *(const bf16x8*)(sb + 8192 + (wc * 64 + ni * 16 + l15) * 64 + (((kk << 2) | lg) ^ xb) * 8);
#pragma unroll
        for (int mi = 0; mi < 4; ++mi)
#pragma unroll
            for (int ni = 0; ni < 4; ++ni) {
                acc[mi][ni] = __builtin_amdgcn_mfma_f32_16x16x32_bf16(af[mi][0], bq[ni][0], acc[mi][ni], 0, 0, 0);
                acc[mi][ni] = __builtin_amdgcn_mfma_f32_16x16x32_bf16(af[mi][1], bq[ni][1], acc[mi][ni], 0, 0, 0);
            }
        if (t + 2 < nt) BARM();
    }

#pragma unroll
    for (int mi = 0; mi < 4; ++mi) {
        int row0 = arow0 + wr * 64 + mi * 16 + lg * 4;
#pragma unroll
        for (int ni = 0; ni < 4; ++ni) {
            int col = brow0 + wc * 64 + ni * 16 + l15;
            float bb = bias[col];
#pragma unroll
            for (int rr = 0; rr < 4; ++rr) {
                int row = row0 + rr;
                if (row < M) {
                    float v = acc[mi][ni][rr] + bb + resid[(size_t)row * N + col];
                    ((float*)outp)[(size_t)row * N + col] = v;
                }
            }
        }
    }
}

// ---------------- Fused attention: blocks [0,1536) global MFMA, [1536,2048) neighborhood ------
__global__ __launch_bounds__(256) void attn_fused(const u16* __restrict__ qkv, const float* __restrict__ ps,
                                                  u16* __restrict__ Z) {
    __shared__ __align__(16) u16 lds0[4 * 16 * PS_STRIDE];
    __shared__ __align__(16) u16 Vt[64 * VT_STRIDE];
    const int tid = threadIdx.x;
    const int lane = tid & 63, wv = tid >> 6;

    if (blockIdx.x >= 1536) {
        // ---- neighborhood attention: 512 blocks x 4 waves; wave = one (b,m) ----
        int idx = blockIdx.x - 1536;
        int b = idx >> 4;
        int m = (idx & 15) * 4 + wv;
        float px = ps[((size_t)b * 64 + m) * 2 + 0] * (1.f / 16.f);
        float py = ps[((size_t)b * 64 + m) * 2 + 1] * (1.f / 16.f);
        int c0 = min(max((int)floorf(px), 0), 13);
        int c1 = min(max((int)ceilf(px), 0), 13);
        int r0 = min(max((int)floorf(py), 0), 13);
        int r1 = min(max((int)ceilf(py), 0), 13);
        int tok[4];
        tok[0] = 1 + r0 * 14 + c0;
        tok[1] = 1 + r1 * 14 + c0;
        tok[2] = 1 + r0 * 14 + c1;
        tok[3] = 1 + r1 * 14 + c1;
        const size_t rowq = ((size_t)b * NT + NGL + m) * 2304;
#pragma unroll 1
        for (int h = 0; h < NHEAD; ++h) {
            float qv = bf2f(qkv[rowq + h * 64 + lane]);
            float a[4];
#pragma unroll
            for (int j = 0; j < 4; ++j) {
                float p = qv * bf2f(qkv[((size_t)b * NT + tok[j]) * 2304 + 768 + h * 64 + lane]);
#pragma unroll
                for (int off = 32; off; off >>= 1) p += __shfl_xor(p, off);
                a[j] = p;
            }
            float mx = fmaxf(fmaxf(a[0], a[1]), fmaxf(a[2], a[3]));
            float e0 = expf(a[0] - mx), e1 = expf(a[1] - mx), e2 = expf(a[2] - mx), e3 = expf(a[3] - mx);
            float inv = 1.f / (e0 + e1 + e2 + e3);
            float v0 = bf2f(qkv[((size_t)b * NT + tok[0]) * 2304 + 1536 + h * 64 + lane]);
            float v1 = bf2f(qkv[((size_t)b * NT + tok[1]) * 2304 + 1536 + h * 64 + lane]);
            float v2 = bf2f(qkv[((size_t)b * NT + tok[2]) * 2304 + 1536 + h * 64 + lane]);
            float v3 = bf2f(qkv[((size_t)b * NT + tok[3]) * 2304 + 1536 + h * 64 + lane]);
            float o = (e0 * v0 + e1 * v1 + e2 * v2 + e3 * v3) * inv;
            Z[((size_t)b * NT + NGL + m) * CDIM + h * 64 + lane] = f2bf(o);
        }
        return;
    }

    // ---- global attention (tokens 0..196) via MFMA ----
    const int blk = blockIdx.x;
    const int qt = blk & 3;
    const int bh = blk >> 2;
    const int h = bh % NHEAD, b = bh / NHEAD;
    const int l15 = lane & 15, lg = lane >> 4;
    const u16* base = qkv + (size_t)b * NT * 2304;

    for (int c = tid; c < 224 * 8; c += 256) {
        int row = c >> 3, ch = c & 7;
        u16x8 v = {};
        if (row < NGL) v = *(const u16x8*)(base + (size_t)row * 2304 + 768 + h * 64 + ch * 8);
        int byte = row * 128 + ((ch * 16) ^ ((row & 7) << 4));
        *(u16x8*)((char*)lds0 + byte) = v;
    }
    for (int c = tid; c < 112 * 8; c += 256) {
        int mp = c >> 3, dch = c & 7;
        int m0 = mp * 2;
        u16x8 a0 = {}, a1 = {};
        if (m0 < NGL)     a0 = *(const u16x8*)(base + (size_t)m0 * 2304 + 1536 + h * 64 + dch * 8);
        if (m0 + 1 < NGL) a1 = *(const u16x8*)(base + (size_t)(m0 + 1) * 2304 + 1536 + h * 64 + dch * 8);
#pragma unroll
        for (int j = 0; j < 8; ++j) {
            u32 pk = (u32)a0[j] | ((u32)a1[j] << 16);
            *(u32*)((char*)Vt + (size_t)(dch * 8 + j) * (VT_STRIDE * 2) + m0 * 2) = pk;
        }
    }
    const int q0 = qt * 64 + wv * 16;
    int qrow = q0 + l15; if (qrow > NGL - 1) qrow = NGL - 1;
    bf16x8 aq0 = *(const bf16x8*)(base + (size_t)qrow * 2304 + h * 64 + lg * 8);
    bf16x8 aq1 = *(const bf16x8*)(base + (size_t)qrow * 2304 + h * 64 + 32 + lg * 8);
    __syncthreads();

    f32x4 s[KT];
    const int sw = (l15 & 7) << 4;
#pragma unroll
    for (int t = 0; t < KT; ++t) {
        const char* krow = (const char*)lds0 + (t * 16 + l15) * 128;
        bf16x8 bk0 = *(const bf16x8*)(krow + ((lg * 16) ^ sw));
        bf16x8 bk1 = *(const bf16x8*)(krow + ((64 + lg * 16) ^ sw));
        f32x4 acc = {};
        acc = __builtin_amdgcn_mfma_f32_16x16x32_bf16(aq0, bk0, acc, 0, 0, 0);
        acc = __builtin_amdgcn_mfma_f32_16x16x32_bf16(aq1, bk1, acc, 0, 0, 0);
        s[t] = acc * 0.125f;
    }
    float mx[4] = {-1e30f, -1e30f, -1e30f, -1e30f};
#pragma unroll
    for (int t = 0; t < KT; ++t)
#pragma unroll
        for (int r = 0; r < 4; ++r) mx[r] = fmaxf(mx[r], s[t][r]);
#pragma unroll
    for (int off = 1; off < 16; off <<= 1)
#pragma unroll
        for (int r = 0; r < 4; ++r) mx[r] = fmaxf(mx[r], __shfl_xor(mx[r], off));
    float sum[4] = {};
#pragma unroll
    for (int t = 0; t < KT; ++t) {
        bool valid = (t * 16 + l15) < NGL;
#pragma unroll
        for (int r = 0; r < 4; ++r) {
            float e = valid ? __expf(s[t][r] - mx[r]) : 0.f;
            s[t][r] = e;
            sum[r] += e;
        }
    }
#pragma unroll
    for (int off = 1; off < 16; off <<= 1)
#pragma unroll
        for (int r = 0; r < 4; ++r) sum[r] += __shfl_xor(sum[r], off);
    float inv[4];
#pragma unroll
    for (int r = 0; r < 4; ++r) inv[r] = 1.f / sum[r];

    __syncthreads();
    u16* Pw = lds0 + wv * 16 * PS_STRIDE;
#pragma unroll
    for (int t = 0; t < KT; ++t)
#pragma unroll
        for (int r = 0; r < 4; ++r)
            Pw[(4 * lg + r) * PS_STRIDE + t * 16 + l15] = f2bf(s[t][r] * inv[r]);

    f32x4 o[4] = {};
#pragma unroll
    for (int ks = 0; ks < 7; ++ks) {
        bf16x8 pa = *(const bf16x8*)(Pw + l15 * PS_STRIDE + ks * 32 + lg * 8);
#pragma unroll
        for (int dt = 0; dt < 4; ++dt) {
            bf16x8 bv = *(const bf16x8*)((const char*)Vt + (size_t)(dt * 16 + l15) * (VT_STRIDE * 2) + ks * 64 + lg * 16);
            o[dt] = __builtin_amdgcn_mfma_f32_16x16x32_bf16(pa, bv, o[dt], 0, 0, 0);
        }
    }
#pragma unroll
    for (int dt = 0; dt < 4; ++dt)
#pragma unroll
        for (int r = 0; r < 4; ++r) {
            int q = q0 + 4 * lg + r;
            if (q < NGL) Z[((size_t)b * NT + q) * CDIM + h * 64 + dt * 16 + l15] = f2bf(o[dt][r]);
        }
}

extern "C" void kernel_launch(void* const* d_in, const int* in_sizes, int n_in,
                              void* d_out, int out_size, void* d_ws, size_t ws_size,
                              hipStream_t stream) {
    const float* x      = (const float*)d_in[0];
    const float* ps     = (const float*)d_in[1];
    const float* n1w    = (const float*)d_in[3];
    const float* n1b    = (const float*)d_in[4];
    const float* qkv_w  = (const float*)d_in[5];
    const float* proj_w = (const float*)d_in[6];
    const float* proj_b = (const float*)d_in[7];
    const float* n2w    = (const float*)d_in[8];
    const float* n2b    = (const float*)d_in[9];
    const float* fc1_w  = (const float*)d_in[10];
    const float* fc1_b  = (const float*)d_in[11];
    const float* fc2_w  = (const float*)d_in[12];
    const float* fc2_b  = (const float*)d_in[13];

    char* ws = (char*)d_ws;
    const int M = 32 * NT;  // 8352
    u16* hbuf  = (u16*)ws;                               // 12,828,672 B
    u16* qkvb  = (u16*)(ws + 12828672);                  // 38,486,016 B
    u16* Zb    = (u16*)(ws + 12828672 + 38486016);       // 12,828,672 B
    u16* Gb    = (u16*)(ws + 12828672);                  // 51,314,688 B (aliases qkv+Z, both dead)
    float* x1  = (float*)(ws + 64143360);                // 25,657,344 B
    u16* wq    = (u16*)(ws + 89800704);
    u16* wp    = wq + 2304 * 768;
    u16* w1    = wp + 768 * 768;
    u16* w2    = w1 + 3072 * 768;

    CvArgs cv;
    cv.in[0] = qkv_w;  cv.out[0] = wq; cv.n4[0] = 2304 * 768 / 4;
    cv.in[1] = proj_w; cv.out[1] = wp; cv.n4[1] = 768 * 768 / 4;
    cv.in[2] = fc1_w;  cv.out[2] = w1; cv.n4[2] = 3072 * 768 / 4;
    cv.in[3] = fc2_w;  cv.out[3] = w2; cv.n4[3] = 768 * 3072 / 4;

    // conv (y=0, 6912 blocks) + LN1 (y=1, 2088 blocks used)
    pre_k<<<dim3(6912, 2), 256, 0, stream>>>(x, n1w, n1b, hbuf, M, cv);
    gemm5<0><<<33 * 9, 512, 0, stream>>>(hbuf, wq, M, 2304, 768, 9, nullptr, qkvb);
    attn_fused<<<2048, 256, 0, stream>>>(qkvb, ps, Zb);
    gemm4n<<<66 * 6, 256, 0, stream>>>(Zb, wp, M, 768, 768, 6, proj_b, x, x1);
    ln_w<<<2088, 256, 0, stream>>>(x1, n2w, n2b, hbuf, M);
    gemm5<2><<<33 * 12, 512, 0, stream>>>(hbuf, w1, M, 3072, 768, 12, fc1_b, Gb);
    gemm4n<<<66 * 6, 256, 0, stream>>>(Gb, w2, M, 768, 3072, 6, fc2_b, x1, (float*)d_out);
}

// Round 9
// 301.946 us; speedup vs baseline: 1.0842x; 1.0001x over previous
//
#include <hip/hip_runtime.h>

typedef unsigned short u16;
typedef unsigned int u32;
typedef u16 u16x8 __attribute__((ext_vector_type(8)));
typedef u16 u16x4 __attribute__((ext_vector_type(4)));
typedef float f32x4 __attribute__((ext_vector_type(4)));
typedef __bf16 bf16x8 __attribute__((ext_vector_type(8)));

#define NHEAD 12
#define NT 261
#define NGL 197
#define CDIM 768
#define KT 14
#define PS_STRIDE 232
#define VT_STRIDE 232

__device__ __forceinline__ float bf2f(u16 u) {
    u32 x = ((u32)u) << 16;
    float f;
    __builtin_memcpy(&f, &x, 4);
    return f;
}
__device__ __forceinline__ u16 f2bf(float f) {
    u32 x;
    __builtin_memcpy(&x, &f, 4);
    x = (x + 0x7fffu + ((x >> 16) & 1u)) >> 16;
    return (u16)x;
}

#define GLD_LDS16(g, l) \
    __builtin_amdgcn_global_load_lds((const __attribute__((address_space(1))) void*)(g), \
                                     (__attribute__((address_space(3))) void*)(l), 16, 0, 0)
#define WAITV(n) asm volatile("s_waitcnt vmcnt(" #n ")" ::: "memory")
#define LGKM0() do { asm volatile("s_waitcnt lgkmcnt(0)" ::: "memory"); __builtin_amdgcn_sched_barrier(0); } while (0)
#define BARM() asm volatile("s_barrier" ::: "memory")

struct CvArgs {
    const float* in[4];
    u16* out[4];
    int n4[4];
};

// ---------------- wave-per-row LayerNorm (768 cols) ----------------
__device__ __forceinline__ void ln_row(const float* __restrict__ in, const float* __restrict__ w,
                                       const float* __restrict__ bia, u16* __restrict__ out,
                                       int row, int lane) {
    const float4* r = (const float4*)(in + (size_t)row * CDIM);
    float4 a = r[lane], b4 = r[lane + 64], c4 = r[lane + 128];
    float s  = a.x + a.y + a.z + a.w + b4.x + b4.y + b4.z + b4.w + c4.x + c4.y + c4.z + c4.w;
    float ss = a.x*a.x + a.y*a.y + a.z*a.z + a.w*a.w
             + b4.x*b4.x + b4.y*b4.y + b4.z*b4.z + b4.w*b4.w
             + c4.x*c4.x + c4.y*c4.y + c4.z*c4.z + c4.w*c4.w;
#pragma unroll
    for (int off = 32; off; off >>= 1) {
        s  += __shfl_xor(s, off);
        ss += __shfl_xor(ss, off);
    }
    float mu = s * (1.f / 768.f);
    float var = ss * (1.f / 768.f) - mu * mu;
    float inv = rsqrtf(var + 1e-5f);
    const float4* wp = (const float4*)w;
    const float4* bp = (const float4*)bia;
    u16* o = out + (size_t)row * CDIM;
#pragma unroll
    for (int t = 0; t < 3; ++t) {
        float4 v = (t == 0) ? a : (t == 1) ? b4 : c4;
        float4 ww = wp[lane + t * 64], bb = bp[lane + t * 64];
        u16x4 ov;
        ov[0] = f2bf((v.x - mu) * inv * ww.x + bb.x);
        ov[1] = f2bf((v.y - mu) * inv * ww.y + bb.y);
        ov[2] = f2bf((v.z - mu) * inv * ww.z + bb.z);
        ov[3] = f2bf((v.w - mu) * inv * ww.w + bb.w);
        *(u16x4*)(o + t * 256 + lane * 4) = ov;
    }
}

__global__ __launch_bounds__(256) void pre_k(const float* __restrict__ x, const float* __restrict__ w,
                                             const float* __restrict__ bia, u16* __restrict__ out,
                                             int nrows, CvArgs cv) {
    if (blockIdx.y == 0) {
        int i = blockIdx.x * 256 + threadIdx.x;
        int s0 = cv.n4[0], s1 = s0 + cv.n4[1], s2 = s1 + cv.n4[2], s3 = s2 + cv.n4[3];
        const float* in;
        u16* o;
        int base;
        if (i < s0)      { in = cv.in[0]; o = cv.out[0]; base = 0; }
        else if (i < s1) { in = cv.in[1]; o = cv.out[1]; base = s0; }
        else if (i < s2) { in = cv.in[2]; o = cv.out[2]; base = s1; }
        else if (i < s3) { in = cv.in[3]; o = cv.out[3]; base = s2; }
        else return;
        int j = i - base;
        float4 v = ((const float4*)in)[j];
        u16x4 ov;
        ov[0] = f2bf(v.x); ov[1] = f2bf(v.y); ov[2] = f2bf(v.z); ov[3] = f2bf(v.w);
        ((u16x4*)o)[j] = ov;
    } else {
        int lane = threadIdx.x & 63, wv = threadIdx.x >> 6;
        int row = blockIdx.x * 4 + wv;
        if (row < nrows) ln_row(x, w, bia, out, row, lane);
    }
}

__global__ __launch_bounds__(256) void ln_w(const float* __restrict__ in, const float* __restrict__ w,
                                            const float* __restrict__ bia, u16* __restrict__ out, int nrows) {
    int lane = threadIdx.x & 63, wv = threadIdx.x >> 6;
    int row = blockIdx.x * 4 + wv;
    if (row < nrows) ln_row(in, w, bia, out, row, lane);
}

// ---------------- 256x256 MFMA GEMM, 4-phase/K-step schedule (m201-style T3+T4+T5) ----------
// 512 thr = 8 waves (2M x 4N), wave tile 128x64, acc[8][4]. BK=64, 2 LDS slots (128 KiB).
// Per K-step t (slot s=t&1): 4 phases; phase p issues 2 global_load_lds of K-step t+1 into
// slot s^1, ds_reads one fragment group, then {barrier; lgkmcnt(0)+sched_barrier;
// setprio(1) 16 MFMA setprio(0); barrier}. Only vmcnt(2) at phase 0 (counted, never 0
// mid-loop): own 8 loads of K-step t drained, 2 just-issued stay in flight.
// Fragment reuse: p0 reads A[mi0-3]+B[ni0-1]; p1 reads B[ni2-3]; p2 reads A[mi4-7]; p3 none.
// EPI: 0 = plain -> bf16; 2 = +bias +gelu(tanh) -> bf16
template <int EPI>
__global__ __launch_bounds__(512, 2) void gemm8(const u16* __restrict__ A, const u16* __restrict__ Bw,
                                                int M, int N, int K, int nbn,
                                                const float* __restrict__ bias,
                                                void* __restrict__ outp) {
    __shared__ __align__(16) u16 sm[2][32768];   // [slot][A 16384 | B 16384]
    const int tid = threadIdx.x;
    const int nwg = gridDim.x;
    const int q = nwg >> 3, r = nwg & 7;
    const int xcd = blockIdx.x & 7, within = blockIdx.x >> 3;
    const int id2 = (xcd < r ? xcd * (q + 1) : r * (q + 1) + (xcd - r) * q) + within;
    const int bm = id2 / nbn, bn = id2 % nbn;
    const int lane = tid & 63, wv = tid >> 6;
    const int wr = wv >> 2, wc = wv & 3;
    const int l15 = lane & 15, lg = lane >> 4;
    const int arow0 = bm * 256, brow0 = bn * 256;
    const int nt = K >> 6;

    const int srow = tid >> 3;
    const int sk = ((tid & 7) ^ (srow & 7)) * 8;
    const u16* gA[4];
    const u16* gB[4];
#pragma unroll
    for (int i = 0; i < 4; ++i) {
        int ar = arow0 + i * 64 + srow;
        if (ar >= M) ar = M - 1;
        gA[i] = A + (size_t)ar * K + sk;
        gB[i] = Bw + (size_t)(brow0 + i * 64 + srow) * K + sk;
    }

    f32x4 acc[8][4] = {};
    const int xb = l15 & 7;
    const int lds_tid = tid * 8;

    // prologue: stage all of K-step 0 into slot 0 (issue order = per-iter order: A0..A3,B0..B3)
    {
        u16* nb = sm[0];
#pragma unroll
        for (int i = 0; i < 4; ++i) GLD_LDS16(gA[i], nb + i * 4096 + lds_tid);
#pragma unroll
        for (int i = 0; i < 4; ++i) GLD_LDS16(gB[i], nb + 16384 + i * 4096 + lds_tid);
    }

    for (int t = 0; t < nt; ++t) {
        const u16* sb = sm[t & 1];
        u16* nb = sm[(t & 1) ^ 1];
        const bool pre = (t + 1 < nt);
        const size_t ko = (size_t)(t + 1) * 64;
        bf16x8 aLo[4][2], aHi[4][2], bLo[2][2], bHi[2][2];

        // ---- phase 0: stage A0,A1(t+1); vmcnt; barrier; read A[mi0-3],B[ni0-1]; 16 MFMA ----
        if (pre) {
            GLD_LDS16(gA[0] + ko, nb + 0 * 4096 + lds_tid);
            GLD_LDS16(gA[1] + ko, nb + 1 * 4096 + lds_tid);
            WAITV(2);
        } else {
            WAITV(0);
        }
        BARM();                                   // slot sb globally valid
#pragma unroll
        for (int mi = 0; mi < 4; ++mi)
#pragma unroll
            for (int kk = 0; kk < 2; ++kk)
                aLo[mi][kk] = *(const bf16x8*)(sb + (wr * 128 + mi * 16 + l15) * 64 + (((kk << 2) | lg) ^ xb) * 8);
#pragma unroll
        for (int ni = 0; ni < 2; ++ni)
#pragma unroll
            for (int kk = 0; kk < 2; ++kk)
                bLo[ni][kk] = *(const bf16x8*)(sb + 16384 + (wc * 64 + ni * 16 + l15) * 64 + (((kk << 2) | lg) ^ xb) * 8);
        LGKM0();
        __builtin_amdgcn_s_setprio(1);
#pragma unroll
        for (int mi = 0; mi < 4; ++mi)
#pragma unroll
            for (int ni = 0; ni < 2; ++ni) {
                acc[mi][ni] = __builtin_amdgcn_mfma_f32_16x16x32_bf16(aLo[mi][0], bLo[ni][0], acc[mi][ni], 0, 0, 0);
                acc[mi][ni] = __builtin_amdgcn_mfma_f32_16x16x32_bf16(aLo[mi][1], bLo[ni][1], acc[mi][ni], 0, 0, 0);
            }
        __builtin_amdgcn_s_setprio(0);
        BARM();

        // ---- phase 1: stage A2,A3(t+1); read B[ni2-3]; 16 MFMA (mi0-3 x ni2-3) ----
        if (pre) {
            GLD_LDS16(gA[2] + ko, nb + 2 * 4096 + lds_tid);
            GLD_LDS16(gA[3] + ko, nb + 3 * 4096 + lds_tid);
        }
#pragma unroll
        for (int ni = 0; ni < 2; ++ni)
#pragma unroll
            for (int kk = 0; kk < 2; ++kk)
                bHi[ni][kk] = *(const bf16x8*)(sb + 16384 + (wc * 64 + (ni + 2) * 16 + l15) * 64 + (((kk << 2) | lg) ^ xb) * 8);
        BARM();
        LGKM0();
        __builtin_amdgcn_s_setprio(1);
#pragma unroll
        for (int mi = 0; mi < 4; ++mi)
#pragma unroll
            for (int ni = 0; ni < 2; ++ni) {
                acc[mi][ni + 2] = __builtin_amdgcn_mfma_f32_16x16x32_bf16(aLo[mi][0], bHi[ni][0], acc[mi][ni + 2], 0, 0, 0);
                acc[mi][ni + 2] = __builtin_amdgcn_mfma_f32_16x16x32_bf16(aLo[mi][1], bHi[ni][1], acc[mi][ni + 2], 0, 0, 0);
            }
        __builtin_amdgcn_s_setprio(0);
        BARM();

        // ---- phase 2: stage B0,B1(t+1); read A[mi4-7]; 16 MFMA (mi4-7 x ni2-3) ----
        if (pre) {
            GLD_LDS16(gB[0] + ko, nb + 16384 + 0 * 4096 + lds_tid);
            GLD_LDS16(gB[1] + ko, nb + 16384 + 1 * 4096 + lds_tid);
        }
#pragma unroll
        for (int mi = 0; mi < 4; ++mi)
#pragma unroll
            for (int kk = 0; kk < 2; ++kk)
                aHi[mi][kk] = *(const bf16x8*)(sb + (wr * 128 + (mi + 4) * 16 + l15) * 64 + (((kk << 2) | lg) ^ xb) * 8);
        BARM();
        LGKM0();
        __builtin_amdgcn_s_setprio(1);
#pragma unroll
        for (int mi = 0; mi < 4; ++mi)
#pragma unroll
            for (int ni = 0; ni < 2; ++ni) {
                acc[mi + 4][ni + 2] = __builtin_amdgcn_mfma_f32_16x16x32_bf16(aHi[mi][0], bHi[ni][0], acc[mi + 4][ni + 2], 0, 0, 0);
                acc[mi + 4][ni + 2] = __builtin_amdgcn_mfma_f32_16x16x32_bf16(aHi[mi][1], bHi[ni][1], acc[mi + 4][ni + 2], 0, 0, 0);
            }
        __builtin_amdgcn_s_setprio(0);
        BARM();

        // ---- phase 3: stage B2,B3(t+1); no reads; 16 MFMA (mi4-7 x ni0-1, regs from p0/p2) ----
        if (pre) {
            GLD_LDS16(gB[2] + ko, nb + 16384 + 2 * 4096 + lds_tid);
            GLD_LDS16(gB[3] + ko, nb + 16384 + 3 * 4096 + lds_tid);
        }
        BARM();
        __builtin_amdgcn_s_setprio(1);
#pragma unroll
        for (int mi = 0; mi < 4; ++mi)
#pragma unroll
            for (int ni = 0; ni < 2; ++ni) {
                acc[mi + 4][ni] = __builtin_amdgcn_mfma_f32_16x16x32_bf16(aHi[mi][0], bLo[ni][0], acc[mi + 4][ni], 0, 0, 0);
                acc[mi + 4][ni] = __builtin_amdgcn_mfma_f32_16x16x32_bf16(aHi[mi][1], bLo[ni][1], acc[mi + 4][ni], 0, 0, 0);
            }
        __builtin_amdgcn_s_setprio(0);
        BARM();
    }

#pragma unroll
    for (int mi = 0; mi < 8; ++mi) {
        int row0 = arow0 + wr * 128 + mi * 16 + lg * 4;
#pragma unroll
        for (int ni = 0; ni < 4; ++ni) {
            int col = brow0 + wc * 64 + ni * 16 + l15;
            float bb = (EPI == 0) ? 0.f : bias[col];
#pragma unroll
            for (int rr = 0; rr < 4; ++rr) {
                int row = row0 + rr;
                if (row < M) {
                    float v = acc[mi][ni][rr] + bb;
                    if (EPI == 2) {
                        float z = v + 0.044715f * v * v * v;
                        v = v / (1.f + __expf(-1.5957691216f * z));
                    }
                    ((u16*)outp)[(size_t)row * N + col] = f2bf(v);
                }
            }
        }
    }
}

// ---------------- 128x128 pipelined GEMM (narrow-N): +bias +resid(fp32) -> fp32 ----------------
__global__ __launch_bounds__(256, 2) void gemm4n(const u16* __restrict__ A, const u16* __restrict__ Bw,
                                                 int M, int N, int K, int nbn,
                                                 const float* __restrict__ bias,
                                                 const float* __restrict__ resid, void* __restrict__ outp) {
    constexpr int SLOT = 128 * 64 + 8192;
    __shared__ __align__(16) u16 sm[2 * SLOT];
    const int tid = threadIdx.x;
    const int nwg = gridDim.x;
    const int q = nwg >> 3, r = nwg & 7;
    const int xcd = blockIdx.x & 7, within = blockIdx.x >> 3;
    const int id2 = (xcd < r ? xcd * (q + 1) : r * (q + 1) + (xcd - r) * q) + within;
    const int bm = id2 / nbn, bn = id2 % nbn;
    const int lane = tid & 63, wv = tid >> 6;
    const int wr = wv >> 1, wc = wv & 1;
    const int l15 = lane & 15, lg = lane >> 4;
    const int arow0 = bm * 128, brow0 = bn * 128;
    const int nt = K >> 6;

    const int srow = tid >> 3;
    const int sk = ((tid & 7) ^ (srow & 7)) * 8;
    const u16* gA[4];
    const u16* gB[4];
#pragma unroll
    for (int i = 0; i < 4; ++i) {
        int ar = arow0 + i * 32 + srow;
        if (ar >= M) ar = M - 1;
        gA[i] = A + (size_t)ar * K + sk;
        gB[i] = Bw + (size_t)(brow0 + i * 32 + srow) * K + sk;
    }

    auto STAGE = [&](int tt) {
        u16* sb = sm + (tt & 1) * SLOT;
        const size_t ko = (size_t)tt * 64;
#pragma unroll
        for (int i = 0; i < 4; ++i) GLD_LDS16(gA[i] + ko, sb + i * 2048 + tid * 8);
#pragma unroll
        for (int i = 0; i < 4; ++i) GLD_LDS16(gB[i] + ko, sb + 8192 + i * 2048 + tid * 8);
    };

    f32x4 acc[4][4] = {};
    const int xb = l15 & 7;

    STAGE(0);
    for (int t = 0; t < nt; ++t) {
        if (t + 1 < nt) {
            STAGE(t + 1);
            WAITV(8);
        } else {
            WAITV(0);
        }
        BARM();
        const u16* sb = sm + (t & 1) * SLOT;
        bf16x8 af[4][2], bq[4][2];
#pragma unroll
        for (int mi = 0; mi < 4; ++mi)
#pragma unroll
            for (int kk = 0; kk < 2; ++kk)
                af[mi][kk] = *(const bf16x8*)(sb + (wr * 64 + mi * 16 + l15) * 64 + (((kk << 2) | lg) ^ xb) * 8);
#pragma unroll
        for (int ni = 0; ni < 4; ++ni)
#pragma unroll
            for (int kk = 0; kk < 2; ++kk)
                bq[ni][kk] = *(const bf16x8*)(sb + 8192 + (wc * 64 + ni * 16 + l15) * 64 + (((kk << 2) | lg) ^ xb) * 8);
#pragma unroll
        for (int mi = 0; mi < 4; ++mi)
#pragma unroll
            for (int ni = 0; ni < 4; ++ni) {
                acc[mi][ni] = __builtin_amdgcn_mfma_f32_16x16x32_bf16(af[mi][0], bq[ni][0], acc[mi][ni], 0, 0, 0);
                acc[mi][ni] = __builtin_amdgcn_mfma_f32_16x16x32_bf16(af[mi][1], bq[ni][1], acc[mi][ni], 0, 0, 0);
            }
        if (t + 2 < nt) BARM();
    }

#pragma unroll
    for (int mi = 0; mi < 4; ++mi) {
        int row0 = arow0 + wr * 64 + mi * 16 + lg * 4;
#pragma unroll
        for (int ni = 0; ni < 4; ++ni) {
            int col = brow0 + wc * 64 + ni * 16 + l15;
            float bb = bias[col];
#pragma unroll
            for (int rr = 0; rr < 4; ++rr) {
                int row = row0 + rr;
                if (row < M) {
                    float v = acc[mi][ni][rr] + bb + resid[(size_t)row * N + col];
                    ((float*)outp)[(size_t)row * N + col] = v;
                }
            }
        }
    }
}

// ---------------- Fused attention: blocks [0,1536) global MFMA, [1536,2048) neighborhood ------
__global__ __launch_bounds__(256) void attn_fused(const u16* __restrict__ qkv, const float* __restrict__ ps,
                                                  u16* __restrict__ Z) {
    __shared__ __align__(16) u16 lds0[4 * 16 * PS_STRIDE];
    __shared__ __align__(16) u16 Vt[64 * VT_STRIDE];
    const int tid = threadIdx.x;
    const int lane = tid & 63, wv = tid >> 6;

    if (blockIdx.x >= 1536) {
        int idx = blockIdx.x - 1536;
        int b = idx >> 4;
        int m = (idx & 15) * 4 + wv;
        float px = ps[((size_t)b * 64 + m) * 2 + 0] * (1.f / 16.f);
        float py = ps[((size_t)b * 64 + m) * 2 + 1] * (1.f / 16.f);
        int c0 = min(max((int)floorf(px), 0), 13);
        int c1 = min(max((int)ceilf(px), 0), 13);
        int r0 = min(max((int)floorf(py), 0), 13);
        int r1 = min(max((int)ceilf(py), 0), 13);
        int tok[4];
        tok[0] = 1 + r0 * 14 + c0;
        tok[1] = 1 + r1 * 14 + c0;
        tok[2] = 1 + r0 * 14 + c1;
        tok[3] = 1 + r1 * 14 + c1;
        const size_t rowq = ((size_t)b * NT + NGL + m) * 2304;
#pragma unroll 1
        for (int h = 0; h < NHEAD; ++h) {
            float qv = bf2f(qkv[rowq + h * 64 + lane]);
            float a[4];
#pragma unroll
            for (int j = 0; j < 4; ++j) {
                float p = qv * bf2f(qkv[((size_t)b * NT + tok[j]) * 2304 + 768 + h * 64 + lane]);
#pragma unroll
                for (int off = 32; off; off >>= 1) p += __shfl_xor(p, off);
                a[j] = p;
            }
            float mx = fmaxf(fmaxf(a[0], a[1]), fmaxf(a[2], a[3]));
            float e0 = expf(a[0] - mx), e1 = expf(a[1] - mx), e2 = expf(a[2] - mx), e3 = expf(a[3] - mx);
            float inv = 1.f / (e0 + e1 + e2 + e3);
            float v0 = bf2f(qkv[((size_t)b * NT + tok[0]) * 2304 + 1536 + h * 64 + lane]);
            float v1 = bf2f(qkv[((size_t)b * NT + tok[1]) * 2304 + 1536 + h * 64 + lane]);
            float v2 = bf2f(qkv[((size_t)b * NT + tok[2]) * 2304 + 1536 + h * 64 + lane]);
            float v3 = bf2f(qkv[((size_t)b * NT + tok[3]) * 2304 + 1536 + h * 64 + lane]);
            float o = (e0 * v0 + e1 * v1 + e2 * v2 + e3 * v3) * inv;
            Z[((size_t)b * NT + NGL + m) * CDIM + h * 64 + lane] = f2bf(o);
        }
        return;
    }

    const int blk = blockIdx.x;
    const int qt = blk & 3;
    const int bh = blk >> 2;
    const int h = bh % NHEAD, b = bh / NHEAD;
    const int l15 = lane & 15, lg = lane >> 4;
    const u16* base = qkv + (size_t)b * NT * 2304;

    for (int c = tid; c < 224 * 8; c += 256) {
        int row = c >> 3, ch = c & 7;
        u16x8 v = {};
        if (row < NGL) v = *(const u16x8*)(base + (size_t)row * 2304 + 768 + h * 64 + ch * 8);
        int byte = row * 128 + ((ch * 16) ^ ((row & 7) << 4));
        *(u16x8*)((char*)lds0 + byte) = v;
    }
    for (int c = tid; c < 112 * 8; c += 256) {
        int mp = c >> 3, dch = c & 7;
        int m0 = mp * 2;
        u16x8 a0 = {}, a1 = {};
        if (m0 < NGL)     a0 = *(const u16x8*)(base + (size_t)m0 * 2304 + 1536 + h * 64 + dch * 8);
        if (m0 + 1 < NGL) a1 = *(const u16x8*)(base + (size_t)(m0 + 1) * 2304 + 1536 + h * 64 + dch * 8);
#pragma unroll
        for (int j = 0; j < 8; ++j) {
            u32 pk = (u32)a0[j] | ((u32)a1[j] << 16);
            *(u32*)((char*)Vt + (size_t)(dch * 8 + j) * (VT_STRIDE * 2) + m0 * 2) = pk;
        }
    }
    const int q0 = qt * 64 + wv * 16;
    int qrow = q0 + l15; if (qrow > NGL - 1) qrow = NGL - 1;
    bf16x8 aq0 = *(const bf16x8*)(base + (size_t)qrow * 2304 + h * 64 + lg * 8);
    bf16x8 aq1 = *(const bf16x8*)(base + (size_t)qrow * 2304 + h * 64 + 32 + lg * 8);
    __syncthreads();

    f32x4 s[KT];
    const int sw = (l15 & 7) << 4;
#pragma unroll
    for (int t = 0; t < KT; ++t) {
        const char* krow = (const char*)lds0 + (t * 16 + l15) * 128;
        bf16x8 bk0 = *(const bf16x8*)(krow + ((lg * 16) ^ sw));
        bf16x8 bk1 = *(const bf16x8*)(krow + ((64 + lg * 16) ^ sw));
        f32x4 acc = {};
        acc = __builtin_amdgcn_mfma_f32_16x16x32_bf16(aq0, bk0, acc, 0, 0, 0);
        acc = __builtin_amdgcn_mfma_f32_16x16x32_bf16(aq1, bk1, acc, 0, 0, 0);
        s[t] = acc * 0.125f;
    }
    float mx[4] = {-1e30f, -1e30f, -1e30f, -1e30f};
#pragma unroll
    for (int t = 0; t < KT; ++t)
#pragma unroll
        for (int r = 0; r < 4; ++r) mx[r] = fmaxf(mx[r], s[t][r]);
#pragma unroll
    for (int off = 1; off < 16; off <<= 1)
#pragma unroll
        for (int r = 0; r < 4; ++r) mx[r] = fmaxf(mx[r], __shfl_xor(mx[r], off));
    float sum[4] = {};
#pragma unroll
    for (int t = 0; t < KT; ++t) {
        bool valid = (t * 16 + l15) < NGL;
#pragma unroll
        for (int r = 0; r < 4; ++r) {
            float e = valid ? __expf(s[t][r] - mx[r]) : 0.f;
            s[t][r] = e;
            sum[r] += e;
        }
    }
#pragma unroll
    for (int off = 1; off < 16; off <<= 1)
#pragma unroll
        for (int r = 0; r < 4; ++r) sum[r] += __shfl_xor(sum[r], off);
    float inv[4];
#pragma unroll
    for (int r = 0; r < 4; ++r) inv[r] = 1.f / sum[r];

    __syncthreads();
    u16* Pw = lds0 + wv * 16 * PS_STRIDE;
#pragma unroll
    for (int t = 0; t < KT; ++t)
#pragma unroll
        for (int r = 0; r < 4; ++r)
            Pw[(4 * lg + r) * PS_STRIDE + t * 16 + l15] = f2bf(s[t][r] * inv[r]);

    f32x4 o[4] = {};
#pragma unroll
    for (int ks = 0; ks < 7; ++ks) {
        bf16x8 pa = *(const bf16x8*)(Pw + l15 * PS_STRIDE + ks * 32 + lg * 8);
#pragma unroll
        for (int dt = 0; dt < 4; ++dt) {
            bf16x8 bv = *(const bf16x8*)((const char*)Vt + (size_t)(dt * 16 + l15) * (VT_STRIDE * 2) + ks * 64 + lg * 16);
            o[dt] = __builtin_amdgcn_mfma_f32_16x16x32_bf16(pa, bv, o[dt], 0, 0, 0);
        }
    }
#pragma unroll
    for (int dt = 0; dt < 4; ++dt)
#pragma unroll
        for (int r = 0; r < 4; ++r) {
            int q = q0 + 4 * lg + r;
            if (q < NGL) Z[((size_t)b * NT + q) * CDIM + h * 64 + dt * 16 + l15] = f2bf(o[dt][r]);
        }
}

extern "C" void kernel_launch(void* const* d_in, const int* in_sizes, int n_in,
                              void* d_out, int out_size, void* d_ws, size_t ws_size,
                              hipStream_t stream) {
    const float* x      = (const float*)d_in[0];
    const float* ps     = (const float*)d_in[1];
    const float* n1w    = (const float*)d_in[3];
    const float* n1b    = (const float*)d_in[4];
    const float* qkv_w  = (const float*)d_in[5];
    const float* proj_w = (const float*)d_in[6];
    const float* proj_b = (const float*)d_in[7];
    const float* n2w    = (const float*)d_in[8];
    const float* n2b    = (const float*)d_in[9];
    const float* fc1_w  = (const float*)d_in[10];
    const float* fc1_b  = (const float*)d_in[11];
    const float* fc2_w  = (const float*)d_in[12];
    const float* fc2_b  = (const float*)d_in[13];

    char* ws = (char*)d_ws;
    const int M = 32 * NT;  // 8352
    u16* hbuf  = (u16*)ws;                               // 12,828,672 B
    u16* qkvb  = (u16*)(ws + 12828672);                  // 38,486,016 B
    u16* Zb    = (u16*)(ws + 12828672 + 38486016);       // 12,828,672 B
    u16* Gb    = (u16*)(ws + 12828672);                  // 51,314,688 B (aliases qkv+Z, both dead)
    float* x1  = (float*)(ws + 64143360);                // 25,657,344 B
    u16* wq    = (u16*)(ws + 89800704);
    u16* wp    = wq + 2304 * 768;
    u16* w1    = wp + 768 * 768;
    u16* w2    = w1 + 3072 * 768;

    CvArgs cv;
    cv.in[0] = qkv_w;  cv.out[0] = wq; cv.n4[0] = 2304 * 768 / 4;
    cv.in[1] = proj_w; cv.out[1] = wp; cv.n4[1] = 768 * 768 / 4;
    cv.in[2] = fc1_w;  cv.out[2] = w1; cv.n4[2] = 3072 * 768 / 4;
    cv.in[3] = fc2_w;  cv.out[3] = w2; cv.n4[3] = 768 * 3072 / 4;

    pre_k<<<dim3(6912, 2), 256, 0, stream>>>(x, n1w, n1b, hbuf, M, cv);
    gemm8<0><<<33 * 9, 512, 0, stream>>>(hbuf, wq, M, 2304, 768, 9, nullptr, qkvb);
    attn_fused<<<2048, 256, 0, stream>>>(qkvb, ps, Zb);
    gemm4n<<<66 * 6, 256, 0, stream>>>(Zb, wp, M, 768, 768, 6, proj_b, x, x1);
    ln_w<<<2088, 256, 0, stream>>>(x1, n2w, n2b, hbuf, M);
    gemm8<2><<<33 * 12, 512, 0, stream>>>(hbuf, w1, M, 3072, 768, 12, fc1_b, Gb);
    gemm4n<<<66 * 6, 256, 0, stream>>>(Gb, w2, M, 768, 3072, 6, fc2_b, x1, (float*)d_out);
}